// Round 1
// baseline (240.454 us; speedup 1.0000x reference)
//
#include <hip/hip_runtime.h>

#define BQ 8
#define NQ 2048
#define ROWS 8      // i-rows per block
#define TPB 256

__global__ void idla_zero_ws(double* __restrict__ ws) {
    if (threadIdx.x < 2) ws[threadIdx.x] = 0.0;
}

__global__ __launch_bounds__(TPB) void idla_main(
        const float* __restrict__ preds,
        const float* __restrict__ targets,
        const float* __restrict__ adj,
        double* __restrict__ ws) {
    // SoA point stage: 6 * 2048 * 4 B = 48 KB LDS
    __shared__ __attribute__((aligned(16))) float px[NQ], py[NQ], pz[NQ];
    __shared__ __attribute__((aligned(16))) float tx[NQ], ty[NQ], tz[NQ];
    __shared__ float red_sq[TPB / 64], red_ad[TPB / 64];

    const int nb_per_batch = NQ / ROWS;               // 256
    const int b  = blockIdx.x / nb_per_batch;
    const int i0 = (blockIdx.x % nb_per_batch) * ROWS;
    const int tid = threadIdx.x;

    // Stage this batch's points into LDS (AoS global -> SoA LDS)
    const float* pb = preds   + (size_t)b * NQ * 3;
    const float* tb = targets + (size_t)b * NQ * 3;
    for (int e = tid; e < NQ * 3; e += TPB) {
        int j = e / 3;
        int c = e - 3 * j;
        float v = pb[e];
        float w = tb[e];
        if (c == 0)      { px[j] = v; tx[j] = w; }
        else if (c == 1) { py[j] = v; ty[j] = w; }
        else             { pz[j] = v; tz[j] = w; }
    }
    __syncthreads();

    float acc_sq = 0.0f;   // sum of ((dp - dt) * a)^2
    float acc_ad = 0.0f;   // sum of a
    const float* adjb = adj + (size_t)b * NQ * NQ;

    #pragma unroll
    for (int ig = 0; ig < ROWS; ig += 4) {
        // Register-cache 4 i-points (broadcast LDS reads: all lanes same addr)
        float pix[4], piy[4], piz[4], tix[4], tiy[4], tiz[4];
        #pragma unroll
        for (int ii = 0; ii < 4; ii++) {
            int i = i0 + ig + ii;
            pix[ii] = px[i]; piy[ii] = py[i]; piz[ii] = pz[i];
            tix[ii] = tx[i]; tiy[ii] = ty[i]; tiz[ii] = tz[i];
        }
        // Sweep j with float4 granularity; 2048 / (256*4) = 2 iterations
        for (int j0 = tid * 4; j0 < NQ; j0 += TPB * 4) {
            float4 vx = *(const float4*)&px[j0];
            float4 vy = *(const float4*)&py[j0];
            float4 vz = *(const float4*)&pz[j0];
            float4 wx = *(const float4*)&tx[j0];
            float4 wy = *(const float4*)&ty[j0];
            float4 wz = *(const float4*)&tz[j0];
            float jx[4] = {vx.x, vx.y, vx.z, vx.w};
            float jy[4] = {vy.x, vy.y, vy.z, vy.w};
            float jz[4] = {vz.x, vz.y, vz.z, vz.w};
            float ux[4] = {wx.x, wx.y, wx.z, wx.w};
            float uy[4] = {wy.x, wy.y, wy.z, wy.w};
            float uz[4] = {wz.x, wz.y, wz.z, wz.w};

            #pragma unroll
            for (int ii = 0; ii < 4; ii++) {
                int i = i0 + ig + ii;
                float4 a4 = *(const float4*)&adjb[(size_t)i * NQ + j0];
                float av[4] = {a4.x, a4.y, a4.z, a4.w};
                #pragma unroll
                for (int jj = 0; jj < 4; jj++) {
                    float dx = pix[ii] - jx[jj];
                    float dy = piy[ii] - jy[jj];
                    float dz = piz[ii] - jz[jj];
                    float dp = sqrtf(dx * dx + dy * dy + dz * dz);
                    float ex = tix[ii] - ux[jj];
                    float ey = tiy[ii] - uy[jj];
                    float ez = tiz[ii] - uz[jj];
                    float dt = sqrtf(ex * ex + ey * ey + ez * ez);
                    float d = (dp - dt) * av[jj];
                    acc_sq += d * d;
                    acc_ad += av[jj];
                }
            }
        }
    }

    // Wave64 shuffle reduction
    #pragma unroll
    for (int off = 32; off > 0; off >>= 1) {
        acc_sq += __shfl_down(acc_sq, off, 64);
        acc_ad += __shfl_down(acc_ad, off, 64);
    }
    const int wave = tid >> 6;
    if ((tid & 63) == 0) { red_sq[wave] = acc_sq; red_ad[wave] = acc_ad; }
    __syncthreads();
    if (tid == 0) {
        float s_sq = 0.0f, s_ad = 0.0f;
        #pragma unroll
        for (int w = 0; w < TPB / 64; w++) { s_sq += red_sq[w]; s_ad += red_ad[w]; }
        atomicAdd(&ws[0], (double)s_sq);
        atomicAdd(&ws[1], (double)s_ad);
    }
}

__global__ void idla_final(const double* __restrict__ ws, float* __restrict__ out) {
    out[0] = (float)(ws[0] / ws[1]);
}

extern "C" void kernel_launch(void* const* d_in, const int* in_sizes, int n_in,
                              void* d_out, int out_size, void* d_ws, size_t ws_size,
                              hipStream_t stream) {
    const float* preds   = (const float*)d_in[0];
    const float* targets = (const float*)d_in[1];
    const float* adj     = (const float*)d_in[2];
    double* ws  = (double*)d_ws;
    float*  out = (float*)d_out;

    hipLaunchKernelGGL(idla_zero_ws, dim3(1), dim3(64), 0, stream, ws);
    const int blocks = BQ * (NQ / ROWS);   // 2048
    hipLaunchKernelGGL(idla_main, dim3(blocks), dim3(TPB), 0, stream,
                       preds, targets, adj, ws);
    hipLaunchKernelGGL(idla_final, dim3(1), dim3(1), 0, stream, ws, out);
}